// Round 1
// baseline (14299.785 us; speedup 1.0000x reference)
//
#include <hip/hip_runtime.h>
#include <math.h>

#define NN 100000
#define NE 1600000
#define DD 64
#define NL 4
#define NH 4
#define NC 16
#define DIN 192
#define SLOPE 0.2f
#define XSTRIDE 196   // 196 % 32 = 4 -> rows {r,r+4,r+8,r+12} give only 2-way bank aliasing (free); 196*4 bytes % 16 == 0 (float4-safe)

__device__ __forceinline__ float atomicMaxF(float* addr, float val) {
  if (val >= 0.f) return __int_as_float(atomicMax((int*)addr, __float_as_int(val)));
  return __uint_as_float(atomicMin((unsigned int*)addr, __float_as_uint(val)));
}

// v[d][h] = sum_c edge_w[d][h*16+c] * att_edge[h][c]
__global__ void k_compute_v(const float* __restrict__ ew, const float* __restrict__ ae,
                            float* __restrict__ v) {
  int d = threadIdx.x >> 2, h = threadIdx.x & 3;
  float s = 0.f;
#pragma unroll
  for (int c = 0; c < NC; ++c) s = fmaf(ew[d * DD + h * NC + c], ae[h * NC + c], s);
  v[d * NH + h] = s;
}

// xh = nf @ W  ;  alpha_src/dst per (node, head)
__global__ void k_xh(const float* __restrict__ nf, const float* __restrict__ W,
                     const float* __restrict__ as_, const float* __restrict__ ad_,
                     float* __restrict__ xh, float* __restrict__ asrc,
                     float* __restrict__ adst) {
  int t = blockIdx.x * 4 + (threadIdx.x >> 6);
  int d = threadIdx.x & 63;
  if (t >= NN) return;
  const float* x = nf + t * DD;
  float acc = 0.f;
#pragma unroll
  for (int k = 0; k < DD; ++k) acc = fmaf(x[k], W[k * DD + d], acc);
  xh[t * DD + d] = acc;
  int h = d >> 4, c = d & 15;
  float ps = acc * as_[h * NC + c];
  float pd = acc * ad_[h * NC + c];
#pragma unroll
  for (int off = 8; off >= 1; off >>= 1) {
    ps += __shfl_xor(ps, off, 64);
    pd += __shfl_xor(pd, off, 64);
  }
  if (c == 0) { asrc[t * NH + h] = ps; adst[t * NH + h] = pd; }
}

__global__ void k_fill(float* __restrict__ accum, float* __restrict__ amax,
                       float* __restrict__ asum) {
  int i = blockIdx.x * 256 + threadIdx.x;
  if (i < NN * DD) accum[i] = 0.f;
  if (i < NN * NH) { amax[i] = -INFINITY; asum[i] = 0.f; }
}

// pass1: alpha_raw = leaky(asrc[src]+adst[dst]+alpha_edge), atomic segment max
// entries i in [0, NE+NN): i>=NE are self loops (src=dst=i-NE, alpha_edge=0)
__global__ void k_pass1(const float* __restrict__ ef, const int* __restrict__ src,
                        const int* __restrict__ dst, const float* __restrict__ v,
                        const float* __restrict__ asrc, const float* __restrict__ adst,
                        float* __restrict__ araw, float* __restrict__ amax) {
  int i = blockIdx.x * 4 + (threadIdx.x >> 6);
  int d = threadIdx.x & 63;
  if (i >= NE + NN) return;
  int s, t;
  float p0 = 0.f, p1 = 0.f, p2 = 0.f, p3 = 0.f;
  if (i < NE) {
    s = src[i]; t = dst[i];
    float x = ef[i * DD + d];
    float4 vv = ((const float4*)v)[d];
    p0 = x * vv.x; p1 = x * vv.y; p2 = x * vv.z; p3 = x * vv.w;
#pragma unroll
    for (int off = 32; off >= 1; off >>= 1) {
      p0 += __shfl_xor(p0, off, 64);
      p1 += __shfl_xor(p1, off, 64);
      p2 += __shfl_xor(p2, off, 64);
      p3 += __shfl_xor(p3, off, 64);
    }
  } else {
    s = t = i - NE;
  }
  if (d < 4) {
    float pe = (d == 0) ? p0 : (d == 1) ? p1 : (d == 2) ? p2 : p3;
    float a = asrc[s * NH + d] + adst[t * NH + d] + pe;
    a = (a > 0.f) ? a : SLOPE * a;
    araw[i * NH + d] = a;
    atomicMaxF(&amax[t * NH + d], a);
  }
}

// pass2: w = exp(raw - amax[dst]); accum[dst] += w*xh[src]; asum[dst,h] += w
__global__ void k_pass2(const float* __restrict__ xh, const int* __restrict__ src,
                        const int* __restrict__ dst, const float* __restrict__ araw,
                        const float* __restrict__ amax, float* __restrict__ accum,
                        float* __restrict__ asum) {
  int i = blockIdx.x * 4 + (threadIdx.x >> 6);
  int d = threadIdx.x & 63;
  if (i >= NE + NN) return;
  int s, t;
  if (i < NE) { s = src[i]; t = dst[i]; }
  else        { s = t = i - NE; }
  int h = d >> 4;
  float w = expf(araw[i * NH + h] - amax[t * NH + h]);
  atomicAdd(&accum[t * DD + d], w * xh[s * DD + d]);
  if ((d & 15) == 0) atomicAdd(&asum[t * NH + h], w);
}

// per-node: conv = accum/(asum+1e-16) + b ; LN ; relu ; nf += relu
__global__ void k_node_fin(float* __restrict__ nf, const float* __restrict__ accum,
                           const float* __restrict__ asum, const float* __restrict__ cb,
                           const float* __restrict__ g, const float* __restrict__ b) {
  int t = blockIdx.x * 4 + (threadIdx.x >> 6);
  int d = threadIdx.x & 63;
  if (t >= NN) return;
  int h = d >> 4;
  float val = accum[t * DD + d] / (asum[t * NH + h] + 1e-16f) + cb[d];
  float m = val;
#pragma unroll
  for (int off = 32; off >= 1; off >>= 1) m += __shfl_xor(m, off, 64);
  m *= (1.f / 64.f);
  float c = val - m;
  float q = c * c;
#pragma unroll
  for (int off = 32; off >= 1; off >>= 1) q += __shfl_xor(q, off, 64);
  float rstd = 1.f / sqrtf(q * (1.f / 64.f) + 1e-5f);
  float y = c * rstd * g[d] + b[d];
  y = fmaxf(y, 0.f);
  nf[t * DD + d] = y + nf[t * DD + d];
}

// fused edge MLP: x=[nf[src],nf[dst],ef] ; h=relu(LN(x@W1+b1)) ; ef = h@W2+b2+ef
__global__ __launch_bounds__(256) void k_edge_mlp(
    const float* __restrict__ nf, float* __restrict__ ef, const int* __restrict__ src,
    const int* __restrict__ dst, const float* __restrict__ W1, const float* __restrict__ b1,
    const float* __restrict__ g, const float* __restrict__ bg,
    const float* __restrict__ W2, const float* __restrict__ b2) {
  __shared__ float X[64 * XSTRIDE];  // ~50.2 KB
  int e0 = blockIdx.x * 64;
  int tid = threadIdx.x;

  // stage X: 64 rows x 192 cols, each row = [nf[src]|nf[dst]|ef]
  for (int idx = tid; idx < 64 * 48; idx += 256) {
    int e = idx / 48, q = idx % 48;
    const float4* sp;
    if (q < 16)      sp = (const float4*)(nf + (size_t)src[e0 + e] * DD) + q;
    else if (q < 32) sp = (const float4*)(nf + (size_t)dst[e0 + e] * DD) + (q - 16);
    else             sp = (const float4*)(ef + (size_t)(e0 + e) * DD) + (q - 32);
    float4 vv = *sp;
    *(float4*)&X[e * XSTRIDE + q * 4] = vv;
  }
  __syncthreads();

  int tm = tid >> 4, tn = tid & 15;  // 16x16; thread -> rows tm*4..+4, cols tn*12..+12
  float acc[4][12];
#pragma unroll
  for (int r = 0; r < 4; ++r)
#pragma unroll
    for (int j = 0; j < 12; ++j) acc[r][j] = 0.f;

  const float* w1p = W1 + tn * 12;
  for (int k = 0; k < DIN; ++k) {
    float wv[12];
    *(float4*)&wv[0] = *(const float4*)(w1p + k * DIN);
    *(float4*)&wv[4] = *(const float4*)(w1p + k * DIN + 4);
    *(float4*)&wv[8] = *(const float4*)(w1p + k * DIN + 8);
#pragma unroll
    for (int r = 0; r < 4; ++r) {
      float xr = X[(tm * 4 + r) * XSTRIDE + k];
#pragma unroll
      for (int j = 0; j < 12; ++j) acc[r][j] = fmaf(xr, wv[j], acc[r][j]);
    }
  }

  // + b1, LayerNorm over 192 (16 tn-lanes x 12 cols), affine, relu
  float b1v[12], gv[12], bgv[12];
  *(float4*)&b1v[0] = *(const float4*)(b1 + tn * 12);
  *(float4*)&b1v[4] = *(const float4*)(b1 + tn * 12 + 4);
  *(float4*)&b1v[8] = *(const float4*)(b1 + tn * 12 + 8);
  *(float4*)&gv[0] = *(const float4*)(g + tn * 12);
  *(float4*)&gv[4] = *(const float4*)(g + tn * 12 + 4);
  *(float4*)&gv[8] = *(const float4*)(g + tn * 12 + 8);
  *(float4*)&bgv[0] = *(const float4*)(bg + tn * 12);
  *(float4*)&bgv[4] = *(const float4*)(bg + tn * 12 + 4);
  *(float4*)&bgv[8] = *(const float4*)(bg + tn * 12 + 8);

#pragma unroll
  for (int r = 0; r < 4; ++r)
#pragma unroll
    for (int j = 0; j < 12; ++j) acc[r][j] += b1v[j];

#pragma unroll
  for (int r = 0; r < 4; ++r) {
    float s = 0.f;
#pragma unroll
    for (int j = 0; j < 12; ++j) s += acc[r][j];
#pragma unroll
    for (int off = 8; off >= 1; off >>= 1) s += __shfl_xor(s, off, 64);
    float mean = s * (1.f / (float)DIN);
    float q = 0.f;
#pragma unroll
    for (int j = 0; j < 12; ++j) { float c = acc[r][j] - mean; q = fmaf(c, c, q); }
#pragma unroll
    for (int off = 8; off >= 1; off >>= 1) q += __shfl_xor(q, off, 64);
    float rstd = 1.f / sqrtf(q * (1.f / (float)DIN) + 1e-5f);
#pragma unroll
    for (int j = 0; j < 12; ++j) {
      float y = (acc[r][j] - mean) * rstd * gv[j] + bgv[j];
      acc[r][j] = fmaxf(y, 0.f);
    }
  }

  __syncthreads();  // done reading X
#pragma unroll
  for (int r = 0; r < 4; ++r) {
#pragma unroll
    for (int j4 = 0; j4 < 3; ++j4) {
      *(float4*)&X[(tm * 4 + r) * XSTRIDE + tn * 12 + j4 * 4] =
          make_float4(acc[r][j4 * 4], acc[r][j4 * 4 + 1], acc[r][j4 * 4 + 2], acc[r][j4 * 4 + 3]);
    }
  }
  __syncthreads();

  // GEMM2: y[64,64] = h @ W2 ; thread -> rows tm*4..+4, cols tn*4..+4
  float a2[4][4];
#pragma unroll
  for (int r = 0; r < 4; ++r)
#pragma unroll
    for (int j = 0; j < 4; ++j) a2[r][j] = 0.f;
  const float* w2p = W2 + tn * 4;
  for (int k = 0; k < DIN; ++k) {
    float wv[4];
    *(float4*)&wv[0] = *(const float4*)(w2p + k * DD);
#pragma unroll
    for (int r = 0; r < 4; ++r) {
      float xr = X[(tm * 4 + r) * XSTRIDE + k];
#pragma unroll
      for (int j = 0; j < 4; ++j) a2[r][j] = fmaf(xr, wv[j], a2[r][j]);
    }
  }
  float b2v[4];
  *(float4*)&b2v[0] = *(const float4*)(b2 + tn * 4);
#pragma unroll
  for (int r = 0; r < 4; ++r) {
    int row = e0 + tm * 4 + r;
    float4 eo = *(const float4*)(ef + (size_t)row * DD + tn * 4);
    float4 o;
    o.x = a2[r][0] + b2v[0] + eo.x;
    o.y = a2[r][1] + b2v[1] + eo.y;
    o.z = a2[r][2] + b2v[2] + eo.z;
    o.w = a2[r][3] + b2v[3] + eo.w;
    *(float4*)(ef + (size_t)row * DD + tn * 4) = o;
  }
}

extern "C" void kernel_launch(void* const* d_in, const int* in_sizes, int n_in,
                              void* d_out, int out_size, void* d_ws, size_t ws_size,
                              hipStream_t stream) {
  const float* node_feats = (const float*)d_in[0];
  const float* edge_feats = (const float*)d_in[1];
  const int*   edge_index = (const int*)d_in[2];
  const float* conv_w  = (const float*)d_in[3];
  const float* att_src = (const float*)d_in[4];
  const float* att_dst = (const float*)d_in[5];
  const float* edge_w  = (const float*)d_in[6];
  const float* att_edge= (const float*)d_in[7];
  const float* conv_b  = (const float*)d_in[8];
  const float* ln_g    = (const float*)d_in[9];
  const float* ln_b    = (const float*)d_in[10];
  const float* up1_w   = (const float*)d_in[11];
  const float* up1_b   = (const float*)d_in[12];
  const float* up_ln_g = (const float*)d_in[13];
  const float* up_ln_b = (const float*)d_in[14];
  const float* up2_w   = (const float*)d_in[15];
  const float* up2_b   = (const float*)d_in[16];

  const int* src = edge_index;
  const int* dst = edge_index + NE;

  float* nf = (float*)d_out;                 // node feats live in d_out
  float* ef = nf + (size_t)NN * DD;          // edge feats live in d_out

  float* w = (float*)d_ws;
  float* xh    = w; w += (size_t)NN * DD;
  float* asrc  = w; w += (size_t)NN * NH;
  float* adst  = w; w += (size_t)NN * NH;
  float* araw  = w; w += (size_t)(NE + NN) * NH;
  float* amax  = w; w += (size_t)NN * NH;
  float* asum  = w; w += (size_t)NN * NH;
  float* accum = w; w += (size_t)NN * DD;
  float* vbuf  = w; w += 256;

  hipMemcpyAsync(nf, node_feats, (size_t)NN * DD * sizeof(float),
                 hipMemcpyDeviceToDevice, stream);
  hipMemcpyAsync(ef, edge_feats, (size_t)NE * DD * sizeof(float),
                 hipMemcpyDeviceToDevice, stream);

  for (int l = 0; l < NL; ++l) {
    k_compute_v<<<1, 256, 0, stream>>>(edge_w + (size_t)l * DD * DD,
                                       att_edge + (size_t)l * NH * NC, vbuf);
    k_xh<<<NN / 4, 256, 0, stream>>>(nf, conv_w + (size_t)l * DD * DD,
                                     att_src + (size_t)l * NH * NC,
                                     att_dst + (size_t)l * NH * NC, xh, asrc, adst);
    k_fill<<<(NN * DD + 255) / 256, 256, 0, stream>>>(accum, amax, asum);
    k_pass1<<<(NE + NN) / 4, 256, 0, stream>>>(ef, src, dst, vbuf, asrc, adst, araw, amax);
    k_pass2<<<(NE + NN) / 4, 256, 0, stream>>>(xh, src, dst, araw, amax, accum, asum);
    k_node_fin<<<NN / 4, 256, 0, stream>>>(nf, accum, asum, conv_b + (size_t)l * DD,
                                           ln_g + (size_t)l * DD, ln_b + (size_t)l * DD);
    k_edge_mlp<<<NE / 64, 256, 0, stream>>>(nf, ef, src, dst,
                                            up1_w + (size_t)l * DIN * DIN,
                                            up1_b + (size_t)l * DIN,
                                            up_ln_g + (size_t)l * DIN,
                                            up_ln_b + (size_t)l * DIN,
                                            up2_w + (size_t)l * DIN * DD,
                                            up2_b + (size_t)l * DD);
  }
}

// Round 3
// 7784.937 us; speedup vs baseline: 1.8369x; 1.8369x over previous
//
#include <hip/hip_runtime.h>
#include <math.h>

#define NN 100000
#define NE 1600000
#define DD 64
#define NL 4
#define NH 4
#define NC 16
#define DIN 192
#define SLOPE 0.2f

typedef __bf16 bf8 __attribute__((ext_vector_type(8)));
typedef float f32x4 __attribute__((ext_vector_type(4)));

__device__ __forceinline__ f32x4 MFMA(bf8 a, bf8 b, f32x4 c) {
  return __builtin_amdgcn_mfma_f32_16x16x32_bf16(a, b, c, 0, 0, 0);
}

__device__ __forceinline__ float atomicMaxF(float* addr, float val) {
  if (val >= 0.f) return __int_as_float(atomicMax((int*)addr, __float_as_int(val)));
  return __uint_as_float(atomicMin((unsigned int*)addr, __float_as_uint(val)));
}

// ---------------- weight packing into MFMA B-fragment layout ----------------
// layout: per layer, per (t,s) tile: 64 lanes x [8 bf16 hi | 8 bf16 lo] (32B/lane)
// element j of lane l = W[k][n], k = s*32 + (l>>4)*8 + j, n = t*16 + (l&15)
__global__ void k_pack_w1(const float* __restrict__ W1, __bf16* __restrict__ W1P) {
  int gidx = blockIdx.x * 256 + threadIdx.x;           // 4 * 12*6*64 = 18432
  if (gidx >= 4 * 4608) return;
  int lyr = gidx / 4608, rem = gidx % 4608;
  int lane = rem & 63, ts = rem >> 6;                  // 0..71
  int s = ts % 6, t = ts / 6;
  const float* Wl = W1 + (size_t)lyr * DIN * DIN;
  __bf16* out = W1P + (size_t)lyr * 73728 + ((size_t)(t * 6 + s) * 64 + lane) * 16;
  int k0 = s * 32 + (lane >> 4) * 8, n = t * 16 + (lane & 15);
#pragma unroll
  for (int j = 0; j < 8; ++j) {
    float v = Wl[(size_t)(k0 + j) * DIN + n];
    __bf16 h = (__bf16)v;
    out[j] = h;
    out[8 + j] = (__bf16)(v - (float)h);
  }
}

__global__ void k_pack_w2(const float* __restrict__ W2, __bf16* __restrict__ W2P) {
  int gidx = blockIdx.x * 256 + threadIdx.x;           // 4 * 4*6*64 = 6144
  if (gidx >= 4 * 1536) return;
  int lyr = gidx / 1536, rem = gidx % 1536;
  int lane = rem & 63, ts = rem >> 6;                  // 0..23
  int s = ts % 6, t = ts / 6;
  const float* Wl = W2 + (size_t)lyr * DIN * DD;
  __bf16* out = W2P + (size_t)lyr * 24576 + ((size_t)(t * 6 + s) * 64 + lane) * 16;
  int k0 = s * 32 + (lane >> 4) * 8, n = t * 16 + (lane & 15);
#pragma unroll
  for (int j = 0; j < 8; ++j) {
    float v = Wl[(size_t)(k0 + j) * DD + n];
    __bf16 h = (__bf16)v;
    out[j] = h;
    out[8 + j] = (__bf16)(v - (float)h);
  }
}

// ---------------- GAT conv path (unchanged from R1) ----------------
__global__ void k_compute_v(const float* __restrict__ ew, const float* __restrict__ ae,
                            float* __restrict__ v) {
  int d = threadIdx.x >> 2, h = threadIdx.x & 3;
  float s = 0.f;
#pragma unroll
  for (int c = 0; c < NC; ++c) s = fmaf(ew[d * DD + h * NC + c], ae[h * NC + c], s);
  v[d * NH + h] = s;
}

__global__ void k_xh(const float* __restrict__ nf, const float* __restrict__ W,
                     const float* __restrict__ as_, const float* __restrict__ ad_,
                     float* __restrict__ xh, float* __restrict__ asrc,
                     float* __restrict__ adst) {
  int t = blockIdx.x * 4 + (threadIdx.x >> 6);
  int d = threadIdx.x & 63;
  if (t >= NN) return;
  const float* x = nf + t * DD;
  float acc = 0.f;
#pragma unroll
  for (int k = 0; k < DD; ++k) acc = fmaf(x[k], W[k * DD + d], acc);
  xh[t * DD + d] = acc;
  int h = d >> 4, c = d & 15;
  float ps = acc * as_[h * NC + c];
  float pd = acc * ad_[h * NC + c];
#pragma unroll
  for (int off = 8; off >= 1; off >>= 1) {
    ps += __shfl_xor(ps, off, 64);
    pd += __shfl_xor(pd, off, 64);
  }
  if (c == 0) { asrc[t * NH + h] = ps; adst[t * NH + h] = pd; }
}

__global__ void k_fill(float* __restrict__ accum, float* __restrict__ amax,
                       float* __restrict__ asum) {
  int i = blockIdx.x * 256 + threadIdx.x;
  if (i < NN * DD) accum[i] = 0.f;
  if (i < NN * NH) { amax[i] = -INFINITY; asum[i] = 0.f; }
}

__global__ void k_pass1(const float* __restrict__ ef, const int* __restrict__ src,
                        const int* __restrict__ dst, const float* __restrict__ v,
                        const float* __restrict__ asrc, const float* __restrict__ adst,
                        float* __restrict__ araw, float* __restrict__ amax) {
  int i = blockIdx.x * 4 + (threadIdx.x >> 6);
  int d = threadIdx.x & 63;
  if (i >= NE + NN) return;
  int s, t;
  float p0 = 0.f, p1 = 0.f, p2 = 0.f, p3 = 0.f;
  if (i < NE) {
    s = src[i]; t = dst[i];
    float x = ef[(size_t)i * DD + d];
    float4 vv = ((const float4*)v)[d];
    p0 = x * vv.x; p1 = x * vv.y; p2 = x * vv.z; p3 = x * vv.w;
#pragma unroll
    for (int off = 32; off >= 1; off >>= 1) {
      p0 += __shfl_xor(p0, off, 64);
      p1 += __shfl_xor(p1, off, 64);
      p2 += __shfl_xor(p2, off, 64);
      p3 += __shfl_xor(p3, off, 64);
    }
  } else {
    s = t = i - NE;
  }
  if (d < 4) {
    float pe = (d == 0) ? p0 : (d == 1) ? p1 : (d == 2) ? p2 : p3;
    float a = asrc[s * NH + d] + adst[t * NH + d] + pe;
    a = (a > 0.f) ? a : SLOPE * a;
    araw[(size_t)i * NH + d] = a;
    atomicMaxF(&amax[t * NH + d], a);
  }
}

__global__ void k_pass2(const float* __restrict__ xh, const int* __restrict__ src,
                        const int* __restrict__ dst, const float* __restrict__ araw,
                        const float* __restrict__ amax, float* __restrict__ accum,
                        float* __restrict__ asum) {
  int i = blockIdx.x * 4 + (threadIdx.x >> 6);
  int d = threadIdx.x & 63;
  if (i >= NE + NN) return;
  int s, t;
  if (i < NE) { s = src[i]; t = dst[i]; }
  else        { s = t = i - NE; }
  int h = d >> 4;
  float w = expf(araw[(size_t)i * NH + h] - amax[t * NH + h]);
  atomicAdd(&accum[t * DD + d], w * xh[(size_t)s * DD + d]);
  if ((d & 15) == 0) atomicAdd(&asum[t * NH + h], w);
}

__global__ void k_node_fin(float* __restrict__ nf, const float* __restrict__ accum,
                           const float* __restrict__ asum, const float* __restrict__ cb,
                           const float* __restrict__ g, const float* __restrict__ b) {
  int t = blockIdx.x * 4 + (threadIdx.x >> 6);
  int d = threadIdx.x & 63;
  if (t >= NN) return;
  int h = d >> 4;
  float val = accum[t * DD + d] / (asum[t * NH + h] + 1e-16f) + cb[d];
  float m = val;
#pragma unroll
  for (int off = 32; off >= 1; off >>= 1) m += __shfl_xor(m, off, 64);
  m *= (1.f / 64.f);
  float c = val - m;
  float q = c * c;
#pragma unroll
  for (int off = 32; off >= 1; off >>= 1) q += __shfl_xor(q, off, 64);
  float rstd = 1.f / sqrtf(q * (1.f / 64.f) + 1e-5f);
  float y = c * rstd * g[d] + b[d];
  y = fmaxf(y, 0.f);
  nf[t * DD + d] = y + nf[t * DD + d];
}

// ---------------- edge MLP via split-bf16 MFMA ----------------
// block = 64 edges, 4 waves; wave w owns edge rows w*16..w*16+15.
// GEMM1: Y1[64,192] = X[64,192] @ W1, X = [nf[src] | nf[dst] | ef]
//   split X and W1 into bf16 hi+lo -> 3 MFMA per (k-step, n-tile)
// LN + relu in C-layout registers; H stored bf16 in LDS (wave-local rows!)
// GEMM2: Y2[64,64] = H @ W2 (H single bf16, W2 hi+lo -> 2 MFMA)
__global__ __launch_bounds__(256, 3) void k_edge_mlp_mfma(
    const float* __restrict__ nf, float* __restrict__ ef,
    const int* __restrict__ src, const int* __restrict__ dst,
    const __bf16* __restrict__ W1P, const float* __restrict__ b1,
    const float* __restrict__ g, const float* __restrict__ bg,
    const __bf16* __restrict__ W2P, const float* __restrict__ b2) {
  __shared__ float EF[64 * 68];      // 17.4 KB, stride 68 -> 2-way bank alias only
  __shared__ __bf16 Hl[64 * 200];    // 25.6 KB, stride 200 -> 2-way alias only
  int tid = threadIdx.x;
  int e0 = blockIdx.x * 64;

  // stage ef tile (coalesced), serves A-frags s=4,5 and the residual
  for (int idx = tid; idx < 64 * 16; idx += 256) {
    int row = idx >> 4, c4 = (idx & 15) * 4;
    float4 v = *(const float4*)(ef + (size_t)(e0 + row) * DD + c4);
    *(float4*)&EF[row * 68 + c4] = v;
  }
  __syncthreads();

  int w = tid >> 6, l = tid & 63;
  int gq = l >> 4, i = l & 15;
  int se = src[e0 + w * 16 + i];
  int de = dst[e0 + w * 16 + i];

  // A fragments (hi/lo) for the 6 K-steps. A[row=l&15][k=(l>>4)*8+j]
  bf8 ahi[6], alo[6];
#pragma unroll
  for (int s = 0; s < 6; ++s) {
    const float* sp;
    if (s < 2)      sp = nf + (size_t)se * DD + s * 32 + gq * 8;
    else if (s < 4) sp = nf + (size_t)de * DD + (s - 2) * 32 + gq * 8;
    else            sp = &EF[(w * 16 + i) * 68 + (s - 4) * 32 + gq * 8];
    float4 v0 = *(const float4*)(sp);
    float4 v1 = *(const float4*)(sp + 4);
    float vv[8] = {v0.x, v0.y, v0.z, v0.w, v1.x, v1.y, v1.z, v1.w};
#pragma unroll
    for (int j = 0; j < 8; ++j) {
      __bf16 h = (__bf16)vv[j];
      ahi[s][j] = h;
      alo[s][j] = (__bf16)(vv[j] - (float)h);
    }
  }

  f32x4 acc[12];
#pragma unroll
  for (int t = 0; t < 12; ++t) acc[t] = (f32x4){0.f, 0.f, 0.f, 0.f};

  const bf8* w1v = (const bf8*)W1P;
#pragma unroll
  for (int s = 0; s < 6; ++s) {
#pragma unroll
    for (int t = 0; t < 12; ++t) {
      int base = ((t * 6 + s) * 64 + l) * 2;
      bf8 bh = w1v[base];
      bf8 bl = w1v[base + 1];
      acc[t] = MFMA(ahi[s], bh, acc[t]);
      acc[t] = MFMA(alo[s], bh, acc[t]);
      acc[t] = MFMA(ahi[s], bl, acc[t]);
    }
  }

  // + b1, LayerNorm per row, affine, relu -> H (bf16) in LDS
  // C layout: col = t*16 + (l&15), LOCAL row = (l>>4)*4 + reg; global row += w*16
  float b1v[12], gv[12], bgv[12];
#pragma unroll
  for (int t = 0; t < 12; ++t) {
    b1v[t] = b1[t * 16 + i];
    gv[t]  = g[t * 16 + i];
    bgv[t] = bg[t * 16 + i];
  }
#pragma unroll
  for (int t = 0; t < 12; ++t)
#pragma unroll
    for (int r = 0; r < 4; ++r) acc[t][r] += b1v[t];

#pragma unroll
  for (int r = 0; r < 4; ++r) {
    float sm = 0.f, sq = 0.f;
#pragma unroll
    for (int t = 0; t < 12; ++t) { float x = acc[t][r]; sm += x; sq = fmaf(x, x, sq); }
#pragma unroll
    for (int off = 8; off >= 1; off >>= 1) {
      sm += __shfl_xor(sm, off, 64);
      sq += __shfl_xor(sq, off, 64);
    }
    float mean = sm * (1.f / (float)DIN);
    float var = sq * (1.f / (float)DIN) - mean * mean;
    float rstd = 1.f / sqrtf(var + 1e-5f);
#pragma unroll
    for (int t = 0; t < 12; ++t) {
      float y = (acc[t][r] - mean) * rstd * gv[t] + bgv[t];
      y = fmaxf(y, 0.f);
      Hl[(w * 16 + gq * 4 + r) * 200 + t * 16 + i] = (__bf16)y;   // FIX: + w*16
    }
  }
  // wave-local: GEMM2 reads only rows w*16..w*16+15, written by this wave.
  // same-__shared__-array dependence -> compiler orders via lgkmcnt.

  f32x4 acc2[4];
#pragma unroll
  for (int t = 0; t < 4; ++t) acc2[t] = (f32x4){0.f, 0.f, 0.f, 0.f};

  const bf8* w2v = (const bf8*)W2P;
#pragma unroll
  for (int s = 0; s < 6; ++s) {
    bf8 ah = *(const bf8*)&Hl[(w * 16 + i) * 200 + s * 32 + gq * 8];
#pragma unroll
    for (int t = 0; t < 4; ++t) {
      int base = ((t * 6 + s) * 64 + l) * 2;
      bf8 bh = w2v[base];
      bf8 bl = w2v[base + 1];
      acc2[t] = MFMA(ah, bh, acc2[t]);
      acc2[t] = MFMA(ah, bl, acc2[t]);
    }
  }

  float b2v[4];
#pragma unroll
  for (int t = 0; t < 4; ++t) b2v[t] = b2[t * 16 + i];

#pragma unroll
  for (int t = 0; t < 4; ++t) {
#pragma unroll
    for (int r = 0; r < 4; ++r) {
      int row = w * 16 + gq * 4 + r;
      float res = acc2[t][r] + b2v[t] + EF[row * 68 + t * 16 + i];
      ef[(size_t)(e0 + row) * DD + t * 16 + i] = res;
    }
  }
}

extern "C" void kernel_launch(void* const* d_in, const int* in_sizes, int n_in,
                              void* d_out, int out_size, void* d_ws, size_t ws_size,
                              hipStream_t stream) {
  const float* node_feats = (const float*)d_in[0];
  const float* edge_feats = (const float*)d_in[1];
  const int*   edge_index = (const int*)d_in[2];
  const float* conv_w  = (const float*)d_in[3];
  const float* att_src = (const float*)d_in[4];
  const float* att_dst = (const float*)d_in[5];
  const float* edge_w  = (const float*)d_in[6];
  const float* att_edge= (const float*)d_in[7];
  const float* conv_b  = (const float*)d_in[8];
  const float* ln_g    = (const float*)d_in[9];
  const float* ln_b    = (const float*)d_in[10];
  const float* up1_w   = (const float*)d_in[11];
  const float* up1_b   = (const float*)d_in[12];
  const float* up_ln_g = (const float*)d_in[13];
  const float* up_ln_b = (const float*)d_in[14];
  const float* up2_w   = (const float*)d_in[15];
  const float* up2_b   = (const float*)d_in[16];

  const int* src = edge_index;
  const int* dst = edge_index + NE;

  float* nf = (float*)d_out;
  float* ef = nf + (size_t)NN * DD;

  float* w = (float*)d_ws;
  float* xh    = w; w += (size_t)NN * DD;
  float* asrc  = w; w += (size_t)NN * NH;
  float* adst  = w; w += (size_t)NN * NH;
  float* araw  = w; w += (size_t)(NE + NN) * NH;
  float* amax  = w; w += (size_t)NN * NH;
  float* asum  = w; w += (size_t)NN * NH;
  float* accum = w; w += (size_t)NN * DD;
  float* vbuf  = w; w += 256;
  __bf16* W1P = (__bf16*)w; w += (size_t)4 * 73728 / 2;   // 4 layers * 147456 B
  __bf16* W2P = (__bf16*)w; w += (size_t)4 * 24576 / 2;   // 4 layers *  49152 B

  hipMemcpyAsync(nf, node_feats, (size_t)NN * DD * sizeof(float),
                 hipMemcpyDeviceToDevice, stream);
  hipMemcpyAsync(ef, edge_feats, (size_t)NE * DD * sizeof(float),
                 hipMemcpyDeviceToDevice, stream);

  k_pack_w1<<<72, 256, 0, stream>>>(up1_w, W1P);
  k_pack_w2<<<24, 256, 0, stream>>>(up2_w, W2P);

  for (int l = 0; l < NL; ++l) {
    k_compute_v<<<1, 256, 0, stream>>>(edge_w + (size_t)l * DD * DD,
                                       att_edge + (size_t)l * NH * NC, vbuf);
    k_xh<<<NN / 4, 256, 0, stream>>>(nf, conv_w + (size_t)l * DD * DD,
                                     att_src + (size_t)l * NH * NC,
                                     att_dst + (size_t)l * NH * NC, xh, asrc, adst);
    k_fill<<<(NN * DD + 255) / 256, 256, 0, stream>>>(accum, amax, asum);
    k_pass1<<<(NE + NN + 3) / 4, 256, 0, stream>>>(ef, src, dst, vbuf, asrc, adst, araw, amax);
    k_pass2<<<(NE + NN + 3) / 4, 256, 0, stream>>>(xh, src, dst, araw, amax, accum, asum);
    k_node_fin<<<NN / 4, 256, 0, stream>>>(nf, accum, asum, conv_b + (size_t)l * DD,
                                           ln_g + (size_t)l * DD, ln_b + (size_t)l * DD);
    k_edge_mlp_mfma<<<NE / 64, 256, 0, stream>>>(
        nf, ef, src, dst,
        W1P + (size_t)l * 73728, up1_b + (size_t)l * DIN,
        up_ln_g + (size_t)l * DIN, up_ln_b + (size_t)l * DIN,
        W2P + (size_t)l * 24576, up2_b + (size_t)l * DD);
  }
}